// Round 1
// baseline (654.656 us; speedup 1.0000x reference)
//
#include <hip/hip_runtime.h>

#define E_CNT 500000
#define N_CNT 50000
#define DD 128
#define HH 256
#define LN_EPS 1e-5f

typedef __attribute__((ext_vector_type(8))) short bh8;   // 8 x bf16 (MFMA A/B frag)
typedef __attribute__((ext_vector_type(4))) float fx4;   // MFMA C/D frag

__device__ __forceinline__ float b2f(short s) {
    return __uint_as_float(((unsigned)(unsigned short)s) << 16);
}
__device__ __forceinline__ short f2b(float f) {
    unsigned x = __float_as_uint(f);
    x += 0x7fffu + ((x >> 16) & 1u);   // RNE
    return (short)(x >> 16);
}
__device__ __forceinline__ fx4 mfma16(bh8 a, bh8 b, fx4 c) {
    return __builtin_amdgcn_mfma_f32_16x16x32_bf16(a, b, c, 0, 0, 0);
}
// byte-offset XOR swizzles for bf16 LDS tiles (G4: break 16/32-way conflicts)
__device__ __forceinline__ int swz128(int row, int k) {   // [*][128] bf16 tile
    return ((row * 128 + k) * 2) ^ ((row & 7) << 4);
}
__device__ __forceinline__ int swz256(int row, int c) {   // [*][256] bf16 tile
    return ((row * 256 + c) * 2) ^ ((row & 7) << 4);
}
__device__ __forceinline__ bh8 pack8(const float* s) {
    float4 f0 = *(const float4*)s, f1 = *(const float4*)(s + 4);
    bh8 v;
    v[0] = f2b(f0.x); v[1] = f2b(f0.y); v[2] = f2b(f0.z); v[3] = f2b(f0.w);
    v[4] = f2b(f1.x); v[5] = f2b(f1.y); v[6] = f2b(f1.z); v[7] = f2b(f1.w);
    return v;
}

// ---------------------------------------------------------------------------
// Weight transpose-convert: dst[n][k] = bf16(src[k][n]); src is [K][N] f32.
// ---------------------------------------------------------------------------
__global__ void wtrans(const float* __restrict__ src, short* __restrict__ dst,
                       int K, int N) {
    int idx = blockIdx.x * 256 + threadIdx.x;
    if (idx >= K * N) return;
    int n = idx / K, k = idx - n * K;
    dst[idx] = f2b(src[(size_t)k * N + n]);
}

// ---------------------------------------------------------------------------
// Table precompute: tabS[n][h] = bf16(nodes[n]@eW1[128:256]), tabR with [256:384].
// BM=128 rows, BN=256, K=128. 8 waves, each 64x64 per table.
// ---------------------------------------------------------------------------
__launch_bounds__(512, 2)
__global__ void table_kernel(const float* __restrict__ nodes,
                             const short* __restrict__ eW1t,   // [256][384]
                             short* __restrict__ tabS, short* __restrict__ tabR) {
    __shared__ char Abuf[128 * 128 * 2];
    const int tid = threadIdx.x;
    const int l = tid & 63, wid = tid >> 6;
    const int wm = wid >> 2, wn = wid & 3;
    const int n0 = blockIdx.x * 128;

    for (int it = 0; it < 4; ++it) {
        int c = tid + 512 * it;
        int row = c >> 4, cc = (c & 15) * 8;
        int n = n0 + row; if (n >= N_CNT) n = N_CNT - 1;
        *(bh8*)(Abuf + swz128(row, cc)) = pack8(nodes + (size_t)n * DD + cc);
    }
    __syncthreads();

    fx4 accS[4][4] = {}; fx4 accR[4][4] = {};
    #pragma unroll
    for (int kk = 0; kk < 4; ++kk) {
        int krow = kk * 32 + (l >> 4) * 8;
        bh8 a[4], bs[4], br[4];
        #pragma unroll
        for (int i = 0; i < 4; ++i)
            a[i] = *(const bh8*)(Abuf + swz128(wm * 64 + 16 * i + (l & 15), krow));
        #pragma unroll
        for (int j = 0; j < 4; ++j) {
            const short* bp = eW1t + (size_t)(wn * 64 + 16 * j + (l & 15)) * 384 + krow;
            bs[j] = *(const bh8*)(bp + 128);
            br[j] = *(const bh8*)(bp + 256);
        }
        #pragma unroll
        for (int i = 0; i < 4; ++i)
            #pragma unroll
            for (int j = 0; j < 4; ++j) {
                accS[i][j] = mfma16(a[i], bs[j], accS[i][j]);
                accR[i][j] = mfma16(a[i], br[j], accR[i][j]);
            }
    }
    #pragma unroll
    for (int i = 0; i < 4; ++i)
        #pragma unroll
        for (int r = 0; r < 4; ++r) {
            int row = wm * 64 + 16 * i + (l >> 4) * 4 + r;
            int n = n0 + row;
            if (n < N_CNT) {
                #pragma unroll
                for (int j = 0; j < 4; ++j) {
                    int col = wn * 64 + 16 * j + (l & 15);
                    tabS[(size_t)n * HH + col] = f2b(accS[i][j][r]);
                    tabR[(size_t)n * HH + col] = f2b(accR[i][j][r]);
                }
            }
        }
}

// ---------------------------------------------------------------------------
// Edge kernel: per 128-edge tile:
//   pre = edges@W1a (MFMA, K=128) + tabS[s] + tabR[r] + eb1
//   h   = relu(LN(pre)) -> bf16 LDS
//   upd = h@eW2 + eb2;  edges_out = upd + edges;  atomicAdd(agg[recv], upd)
// ---------------------------------------------------------------------------
__launch_bounds__(512, 2)
__global__ void edge_kernel(const float* __restrict__ edges,
                            const int* __restrict__ senders,
                            const int* __restrict__ receivers,
                            const short* __restrict__ tabS,
                            const short* __restrict__ tabR,
                            const short* __restrict__ eW1t,   // [256][384]
                            const short* __restrict__ eW2t,   // [128][256]
                            const float* __restrict__ eb1,
                            const float* __restrict__ eg,
                            const float* __restrict__ ebt,
                            const float* __restrict__ eb2,
                            float* __restrict__ agg,
                            float* __restrict__ edges_out) {
    __shared__ char Abuf[128 * 128 * 2];   // edges tile (bf16, swizzled) + residual src
    __shared__ char Sbuf[128 * 256 * 2];   // gathered table sum; later H
    __shared__ float P[128][4][2];         // LN partials [row][wave-n][sum,sumsq]
    __shared__ int isend[128];
    __shared__ int irecv[128];

    const int tid = threadIdx.x;
    const int l = tid & 63, wid = tid >> 6;
    const int e0 = blockIdx.x * 128;

    if (tid < 128) {
        int e = e0 + tid; if (e >= E_CNT) e = E_CNT - 1;
        isend[tid] = senders[e];
        irecv[tid] = receivers[e];
    }
    __syncthreads();

    // stage A: edges rows -> bf16
    for (int it = 0; it < 4; ++it) {
        int c = tid + 512 * it;
        int row = c >> 4, cc = (c & 15) * 8;
        int e = e0 + row; if (e >= E_CNT) e = E_CNT - 1;
        *(bh8*)(Abuf + swz128(row, cc)) = pack8(edges + (size_t)e * DD + cc);
    }
    // stage S = tabS[sender] + tabR[receiver] (bf16 sum)
    for (int it = 0; it < 8; ++it) {
        int c = tid + 512 * it;
        int row = c >> 5, cc = (c & 31) * 8;
        bh8 ts = *(const bh8*)(tabS + (size_t)isend[row] * HH + cc);
        bh8 tr = *(const bh8*)(tabR + (size_t)irecv[row] * HH + cc);
        bh8 v;
        #pragma unroll
        for (int q = 0; q < 8; ++q) v[q] = f2b(b2f(ts[q]) + b2f(tr[q]));
        *(bh8*)(Sbuf + swz256(row, cc)) = v;
    }
    __syncthreads();

    // GEMM1: A[128x128] @ W1a^T-stored -> acc[128x256]; wave = 64 rows x 64 cols
    const int wm = wid >> 2, wn = wid & 3;
    fx4 acc[4][4] = {};
    #pragma unroll
    for (int kk = 0; kk < 4; ++kk) {
        int krow = kk * 32 + (l >> 4) * 8;
        bh8 a[4], b[4];
        #pragma unroll
        for (int i = 0; i < 4; ++i)
            a[i] = *(const bh8*)(Abuf + swz128(wm * 64 + 16 * i + (l & 15), krow));
        #pragma unroll
        for (int j = 0; j < 4; ++j)
            b[j] = *(const bh8*)(eW1t + (size_t)(wn * 64 + 16 * j + (l & 15)) * 384 + krow);
        #pragma unroll
        for (int i = 0; i < 4; ++i)
            #pragma unroll
            for (int j = 0; j < 4; ++j)
                acc[i][j] = mfma16(a[i], b[j], acc[i][j]);
    }

    // epilogue 1: + table-sum + eb1, LN partial sums
    float eb1c[4], egc[4], ebtc[4];
    #pragma unroll
    for (int j = 0; j < 4; ++j) {
        int col = wn * 64 + 16 * j + (l & 15);
        eb1c[j] = eb1[col]; egc[j] = eg[col]; ebtc[j] = ebt[col];
    }
    #pragma unroll
    for (int i = 0; i < 4; ++i)
        #pragma unroll
        for (int r = 0; r < 4; ++r) {
            int row = wm * 64 + 16 * i + (l >> 4) * 4 + r;
            float s = 0.f, q = 0.f;
            #pragma unroll
            for (int j = 0; j < 4; ++j) {
                int col = wn * 64 + 16 * j + (l & 15);
                float v = acc[i][j][r] + eb1c[j] +
                          b2f(*(const short*)(Sbuf + swz256(row, col)));
                acc[i][j][r] = v;
                s += v; q += v * v;
            }
            #pragma unroll
            for (int m = 1; m < 16; m <<= 1) {
                s += __shfl_xor(s, m);
                q += __shfl_xor(q, m);
            }
            if ((l & 15) == 0) { P[row][wn][0] = s; P[row][wn][1] = q; }
        }
    __syncthreads();   // all Sbuf reads done; partials visible

    // epilogue 2: LN + relu -> bf16 H (overwrites Sbuf)
    #pragma unroll
    for (int i = 0; i < 4; ++i)
        #pragma unroll
        for (int r = 0; r < 4; ++r) {
            int row = wm * 64 + 16 * i + (l >> 4) * 4 + r;
            float s = P[row][0][0] + P[row][1][0] + P[row][2][0] + P[row][3][0];
            float q = P[row][0][1] + P[row][1][1] + P[row][2][1] + P[row][3][1];
            float mean = s * (1.0f / 256.0f);
            float var = q * (1.0f / 256.0f) - mean * mean;
            float rstd = rsqrtf(var + LN_EPS);
            #pragma unroll
            for (int j = 0; j < 4; ++j) {
                int col = wn * 64 + 16 * j + (l & 15);
                float v = (acc[i][j][r] - mean) * rstd * egc[j] + ebtc[j];
                v = fmaxf(v, 0.0f);
                *(short*)(Sbuf + swz256(row, col)) = f2b(v);
            }
        }
    __syncthreads();

    // GEMM2: H[128x256] @ eW2 -> [128x128]; wave = 32 rows x 64 cols
    const int wm2 = wid >> 1, wn2 = wid & 1;
    fx4 acc2[2][4] = {};
    #pragma unroll
    for (int kk = 0; kk < 8; ++kk) {
        int krow = kk * 32 + (l >> 4) * 8;
        bh8 a[2], b[4];
        #pragma unroll
        for (int i = 0; i < 2; ++i)
            a[i] = *(const bh8*)(Sbuf + swz256(wm2 * 32 + 16 * i + (l & 15), krow));
        #pragma unroll
        for (int j = 0; j < 4; ++j)
            b[j] = *(const bh8*)(eW2t + (size_t)(wn2 * 64 + 16 * j + (l & 15)) * 256 + krow);
        #pragma unroll
        for (int i = 0; i < 2; ++i)
            #pragma unroll
            for (int j = 0; j < 4; ++j)
                acc2[i][j] = mfma16(a[i], b[j], acc2[i][j]);
    }
    float eb2c[4];
    #pragma unroll
    for (int j = 0; j < 4; ++j) eb2c[j] = eb2[wn2 * 64 + 16 * j + (l & 15)];
    #pragma unroll
    for (int i = 0; i < 2; ++i)
        #pragma unroll
        for (int r = 0; r < 4; ++r) {
            int row = wm2 * 32 + 16 * i + (l >> 4) * 4 + r;
            int e = e0 + row;
            if (e < E_CNT) {
                int rcv = irecv[row];
                #pragma unroll
                for (int j = 0; j < 4; ++j) {
                    int col = wn2 * 64 + 16 * j + (l & 15);
                    float upd = acc2[i][j][r] + eb2c[j];
                    float res = b2f(*(const short*)(Abuf + swz128(row, col)));
                    edges_out[(size_t)e * DD + col] = upd + res;
                    atomicAdd(agg + (size_t)rcv * DD + col, upd);
                }
            }
        }
}

// ---------------------------------------------------------------------------
// Node kernel: nx=[nodes|agg] (K=256) -> LN/relu -> @nW2 + nb2 + nodes
// ---------------------------------------------------------------------------
__launch_bounds__(512, 2)
__global__ void node_kernel(const float* __restrict__ nodes,
                            const float* __restrict__ agg,
                            const short* __restrict__ nW1t,   // [256][256]
                            const short* __restrict__ nW2t,   // [128][256]
                            const float* __restrict__ nb1,
                            const float* __restrict__ ng,
                            const float* __restrict__ nbt,
                            const float* __restrict__ nb2,
                            float* __restrict__ nodes_out) {
    __shared__ char Abuf[128 * 256 * 2];
    __shared__ char Hbuf[128 * 256 * 2];
    __shared__ float P[128][4][2];

    const int tid = threadIdx.x;
    const int l = tid & 63, wid = tid >> 6;
    const int n0 = blockIdx.x * 128;

    for (int it = 0; it < 8; ++it) {
        int c = tid + 512 * it;
        int row = c >> 5, cc = (c & 31) * 8;
        int n = n0 + row; if (n >= N_CNT) n = N_CNT - 1;
        const float* s = (cc < DD) ? (nodes + (size_t)n * DD + cc)
                                   : (agg + (size_t)n * DD + (cc - DD));
        *(bh8*)(Abuf + swz256(row, cc)) = pack8(s);
    }
    __syncthreads();

    const int wm = wid >> 2, wn = wid & 3;
    fx4 acc[4][4] = {};
    #pragma unroll
    for (int kk = 0; kk < 8; ++kk) {
        int krow = kk * 32 + (l >> 4) * 8;
        bh8 a[4], b[4];
        #pragma unroll
        for (int i = 0; i < 4; ++i)
            a[i] = *(const bh8*)(Abuf + swz256(wm * 64 + 16 * i + (l & 15), krow));
        #pragma unroll
        for (int j = 0; j < 4; ++j)
            b[j] = *(const bh8*)(nW1t + (size_t)(wn * 64 + 16 * j + (l & 15)) * 256 + krow);
        #pragma unroll
        for (int i = 0; i < 4; ++i)
            #pragma unroll
            for (int j = 0; j < 4; ++j)
                acc[i][j] = mfma16(a[i], b[j], acc[i][j]);
    }

    float nb1c[4], ngc[4], nbtc[4];
    #pragma unroll
    for (int j = 0; j < 4; ++j) {
        int col = wn * 64 + 16 * j + (l & 15);
        nb1c[j] = nb1[col]; ngc[j] = ng[col]; nbtc[j] = nbt[col];
    }
    #pragma unroll
    for (int i = 0; i < 4; ++i)
        #pragma unroll
        for (int r = 0; r < 4; ++r) {
            int row = wm * 64 + 16 * i + (l >> 4) * 4 + r;
            float s = 0.f, q = 0.f;
            #pragma unroll
            for (int j = 0; j < 4; ++j) {
                float v = acc[i][j][r] + nb1c[j];
                acc[i][j][r] = v;
                s += v; q += v * v;
            }
            #pragma unroll
            for (int m = 1; m < 16; m <<= 1) {
                s += __shfl_xor(s, m);
                q += __shfl_xor(q, m);
            }
            if ((l & 15) == 0) { P[row][wn][0] = s; P[row][wn][1] = q; }
        }
    __syncthreads();

    #pragma unroll
    for (int i = 0; i < 4; ++i)
        #pragma unroll
        for (int r = 0; r < 4; ++r) {
            int row = wm * 64 + 16 * i + (l >> 4) * 4 + r;
            float s = P[row][0][0] + P[row][1][0] + P[row][2][0] + P[row][3][0];
            float q = P[row][0][1] + P[row][1][1] + P[row][2][1] + P[row][3][1];
            float mean = s * (1.0f / 256.0f);
            float var = q * (1.0f / 256.0f) - mean * mean;
            float rstd = rsqrtf(var + LN_EPS);
            #pragma unroll
            for (int j = 0; j < 4; ++j) {
                int col = wn * 64 + 16 * j + (l & 15);
                float v = (acc[i][j][r] - mean) * rstd * ngc[j] + nbtc[j];
                v = fmaxf(v, 0.0f);
                *(short*)(Hbuf + swz256(row, col)) = f2b(v);
            }
        }
    __syncthreads();

    const int wm2 = wid >> 1, wn2 = wid & 1;
    fx4 acc2[2][4] = {};
    #pragma unroll
    for (int kk = 0; kk < 8; ++kk) {
        int krow = kk * 32 + (l >> 4) * 8;
        bh8 a[2], b[4];
        #pragma unroll
        for (int i = 0; i < 2; ++i)
            a[i] = *(const bh8*)(Hbuf + swz256(wm2 * 32 + 16 * i + (l & 15), krow));
        #pragma unroll
        for (int j = 0; j < 4; ++j)
            b[j] = *(const bh8*)(nW2t + (size_t)(wn2 * 64 + 16 * j + (l & 15)) * 256 + krow);
        #pragma unroll
        for (int i = 0; i < 2; ++i)
            #pragma unroll
            for (int j = 0; j < 4; ++j)
                acc2[i][j] = mfma16(a[i], b[j], acc2[i][j]);
    }
    float nb2c[4];
    #pragma unroll
    for (int j = 0; j < 4; ++j) nb2c[j] = nb2[wn2 * 64 + 16 * j + (l & 15)];
    #pragma unroll
    for (int i = 0; i < 2; ++i)
        #pragma unroll
        for (int r = 0; r < 4; ++r) {
            int row = wm2 * 32 + 16 * i + (l >> 4) * 4 + r;
            int n = n0 + row;
            if (n < N_CNT) {
                #pragma unroll
                for (int j = 0; j < 4; ++j) {
                    int col = wn2 * 64 + 16 * j + (l & 15);
                    float v = acc2[i][j][r] + nb2c[j] + nodes[(size_t)n * DD + col];
                    nodes_out[(size_t)n * DD + col] = v;
                }
            }
        }
}

// ---------------------------------------------------------------------------
extern "C" void kernel_launch(void* const* d_in, const int* in_sizes, int n_in,
                              void* d_out, int out_size, void* d_ws, size_t ws_size,
                              hipStream_t stream) {
    const float* nodes = (const float*)d_in[0];
    const float* edges = (const float*)d_in[1];
    const int* senders = (const int*)d_in[2];
    const int* receivers = (const int*)d_in[3];
    const float* eW1 = (const float*)d_in[4];
    const float* eb1 = (const float*)d_in[5];
    const float* eg  = (const float*)d_in[6];
    const float* ebt = (const float*)d_in[7];
    const float* eW2 = (const float*)d_in[8];
    const float* eb2 = (const float*)d_in[9];
    const float* nW1 = (const float*)d_in[10];
    const float* nb1 = (const float*)d_in[11];
    const float* ng  = (const float*)d_in[12];
    const float* nbt = (const float*)d_in[13];
    const float* nW2 = (const float*)d_in[14];
    const float* nb2 = (const float*)d_in[15];

    char* ws = (char*)d_ws;
    float* agg  = (float*)(ws + 0);             // 25,600,000 B
    short* eW1t = (short*)(ws + 25600000);      //    196,608 B [256][384]
    short* eW2t = (short*)(ws + 25796608);      //     65,536 B [128][256]
    short* nW1t = (short*)(ws + 25862144);      //    131,072 B [256][256]
    short* nW2t = (short*)(ws + 25993216);      //     65,536 B [128][256]
    short* tabS = (short*)(ws + 26058752);      // 25,600,000 B [N][256]
    short* tabR = (short*)(ws + 51658752);      // 25,600,000 B [N][256]

    float* nodes_out = (float*)d_out;
    float* edges_out = nodes_out + (size_t)N_CNT * DD;

    hipMemsetAsync(agg, 0, (size_t)N_CNT * DD * sizeof(float), stream);

    wtrans<<<(384 * 256 + 255) / 256, 256, 0, stream>>>(eW1, eW1t, 384, 256);
    wtrans<<<(256 * 128 + 255) / 256, 256, 0, stream>>>(eW2, eW2t, 256, 128);
    wtrans<<<(256 * 256 + 255) / 256, 256, 0, stream>>>(nW1, nW1t, 256, 256);
    wtrans<<<(256 * 128 + 255) / 256, 256, 0, stream>>>(nW2, nW2t, 256, 128);

    table_kernel<<<(N_CNT + 127) / 128, 512, 0, stream>>>(nodes, eW1t, tabS, tabR);

    edge_kernel<<<(E_CNT + 127) / 128, 512, 0, stream>>>(
        edges, senders, receivers, tabS, tabR, eW1t, eW2t,
        eb1, eg, ebt, eb2, agg, edges_out);

    node_kernel<<<(N_CNT + 127) / 128, 512, 0, stream>>>(
        nodes, agg, nW1t, nW2t, nb1, ng, nbt, nb2, nodes_out);
}

// Round 2
// 618.381 us; speedup vs baseline: 1.0587x; 1.0587x over previous
//
#include <hip/hip_runtime.h>

#define E_CNT 500000
#define N_CNT 50000
#define DD 128
#define HH 256
#define LN_EPS 1e-5f

typedef __attribute__((ext_vector_type(8))) short bh8;   // 8 x bf16 (MFMA A/B frag)
typedef __attribute__((ext_vector_type(4))) float fx4;   // MFMA C/D frag

__device__ __forceinline__ float b2f(short s) {
    return __uint_as_float(((unsigned)(unsigned short)s) << 16);
}
__device__ __forceinline__ short f2b(float f) {
    unsigned x = __float_as_uint(f);
    x += 0x7fffu + ((x >> 16) & 1u);   // RNE
    return (short)(x >> 16);
}
__device__ __forceinline__ fx4 mfma16(bh8 a, bh8 b, fx4 c) {
    return __builtin_amdgcn_mfma_f32_16x16x32_bf16(a, b, c, 0, 0, 0);
}
// byte-offset XOR swizzles for bf16 LDS tiles (G4: break 16/32-way conflicts)
__device__ __forceinline__ int swz128(int row, int k) {   // [*][128] bf16 tile
    return ((row * 128 + k) * 2) ^ ((row & 7) << 4);
}
__device__ __forceinline__ int swz256(int row, int c) {   // [*][256] bf16 tile
    return ((row * 256 + c) * 2) ^ ((row & 7) << 4);
}
__device__ __forceinline__ bh8 pack8(const float* s) {
    float4 f0 = *(const float4*)s, f1 = *(const float4*)(s + 4);
    bh8 v;
    v[0] = f2b(f0.x); v[1] = f2b(f0.y); v[2] = f2b(f0.z); v[3] = f2b(f0.w);
    v[4] = f2b(f1.x); v[5] = f2b(f1.y); v[6] = f2b(f1.z); v[7] = f2b(f1.w);
    return v;
}

// ---------------------------------------------------------------------------
// Weight transpose-convert: dst[n][k] = bf16(src[k][n]); src is [K][N] f32.
// ---------------------------------------------------------------------------
__global__ void wtrans(const float* __restrict__ src, short* __restrict__ dst,
                       int K, int N) {
    int idx = blockIdx.x * 256 + threadIdx.x;
    if (idx >= K * N) return;
    int n = idx / K, k = idx - n * K;
    dst[idx] = f2b(src[(size_t)k * N + n]);
}

// ---------------------------------------------------------------------------
// Table precompute: tabS[n][h] = bf16(nodes[n]@eW1[128:256]), tabR with [256:384].
// ---------------------------------------------------------------------------
__launch_bounds__(512, 2)
__global__ void table_kernel(const float* __restrict__ nodes,
                             const short* __restrict__ eW1t,   // [256][384]
                             short* __restrict__ tabS, short* __restrict__ tabR) {
    __shared__ char Abuf[128 * 128 * 2];
    const int tid = threadIdx.x;
    const int l = tid & 63, wid = tid >> 6;
    const int wm = wid >> 2, wn = wid & 3;
    const int n0 = blockIdx.x * 128;

    for (int it = 0; it < 4; ++it) {
        int c = tid + 512 * it;
        int row = c >> 4, cc = (c & 15) * 8;
        int n = n0 + row; if (n >= N_CNT) n = N_CNT - 1;
        *(bh8*)(Abuf + swz128(row, cc)) = pack8(nodes + (size_t)n * DD + cc);
    }
    __syncthreads();

    fx4 accS[4][4] = {}; fx4 accR[4][4] = {};
    #pragma unroll
    for (int kk = 0; kk < 4; ++kk) {
        int krow = kk * 32 + (l >> 4) * 8;
        bh8 a[4], bs[4], br[4];
        #pragma unroll
        for (int i = 0; i < 4; ++i)
            a[i] = *(const bh8*)(Abuf + swz128(wm * 64 + 16 * i + (l & 15), krow));
        #pragma unroll
        for (int j = 0; j < 4; ++j) {
            const short* bp = eW1t + (size_t)(wn * 64 + 16 * j + (l & 15)) * 384 + krow;
            bs[j] = *(const bh8*)(bp + 128);
            br[j] = *(const bh8*)(bp + 256);
        }
        #pragma unroll
        for (int i = 0; i < 4; ++i)
            #pragma unroll
            for (int j = 0; j < 4; ++j) {
                accS[i][j] = mfma16(a[i], bs[j], accS[i][j]);
                accR[i][j] = mfma16(a[i], br[j], accR[i][j]);
            }
    }
    #pragma unroll
    for (int i = 0; i < 4; ++i)
        #pragma unroll
        for (int r = 0; r < 4; ++r) {
            int row = wm * 64 + 16 * i + (l >> 4) * 4 + r;
            int n = n0 + row;
            if (n < N_CNT) {
                #pragma unroll
                for (int j = 0; j < 4; ++j) {
                    int col = wn * 64 + 16 * j + (l & 15);
                    tabS[(size_t)n * HH + col] = f2b(accS[i][j][r]);
                    tabR[(size_t)n * HH + col] = f2b(accR[i][j][r]);
                }
            }
        }
}

// ---------------------------------------------------------------------------
// Edge kernel, BM=64 (LDS ~52KB -> 2 blocks/CU, 16 waves/CU):
//   pre = edges@W1a (MFMA, K=128) + tabS[s] + tabR[r] + eb1
//   h   = relu(LN(pre)) -> bf16 LDS
//   upd = h@eW2 + eb2;  edges_out = upd + edges;  atomicAdd(agg[recv], upd)
// Table gathers issued into registers BEFORE GEMM1 (T14 async split).
// ---------------------------------------------------------------------------
__launch_bounds__(512, 4)
__global__ void edge_kernel(const float* __restrict__ edges,
                            const int* __restrict__ senders,
                            const int* __restrict__ receivers,
                            const short* __restrict__ tabS,
                            const short* __restrict__ tabR,
                            const short* __restrict__ eW1t,   // [256][384]
                            const short* __restrict__ eW2t,   // [128][256]
                            const float* __restrict__ eb1,
                            const float* __restrict__ eg,
                            const float* __restrict__ ebt,
                            const float* __restrict__ eb2,
                            float* __restrict__ agg,
                            float* __restrict__ edges_out) {
    __shared__ char Abuf[64 * 128 * 2];   // edges tile (bf16, swizzled; also residual src)
    __shared__ char Sbuf[64 * 256 * 2];   // gathered table sum; later H
    __shared__ float P[64][4][2];         // LN partials [row][wave-n][sum,sumsq]
    __shared__ int irecv[64];

    const int tid = threadIdx.x;
    const int l = tid & 63, wid = tid >> 6;
    const int e0 = blockIdx.x * 64;

    if (tid < 64) {
        int e = e0 + tid; if (e >= E_CNT) e = E_CNT - 1;
        irecv[tid] = receivers[e];
    }

    // stage A: 64 rows x 128 cols -> bf16 LDS (1024 chunks / 512 thr = 2 iters)
    #pragma unroll
    for (int it = 0; it < 2; ++it) {
        int c = tid + 512 * it;
        int row = c >> 4, cc = (c & 15) * 8;
        int e = e0 + row; if (e >= E_CNT) e = E_CNT - 1;
        *(bh8*)(Abuf + swz128(row, cc)) = pack8(edges + (size_t)e * DD + cc);
    }
    // issue table gathers into registers (consumed after GEMM1)
    bh8 ts[4], tr[4];
    #pragma unroll
    for (int it = 0; it < 4; ++it) {
        int c = tid + 512 * it;
        int row = c >> 5, cc = (c & 31) * 8;
        int e = e0 + row; if (e >= E_CNT) e = E_CNT - 1;
        int sn = senders[e], rn = receivers[e];
        ts[it] = *(const bh8*)(tabS + (size_t)sn * HH + cc);
        tr[it] = *(const bh8*)(tabR + (size_t)rn * HH + cc);
    }
    __syncthreads();

    // GEMM1: A[64x128] @ W1a -> acc[64x256]; wave = 32 rows x 64 cols
    const int wm = wid >> 2, wn = wid & 3;
    fx4 acc[2][4] = {};
    #pragma unroll
    for (int kk = 0; kk < 4; ++kk) {
        int krow = kk * 32 + (l >> 4) * 8;
        bh8 a[2], b[4];
        #pragma unroll
        for (int i = 0; i < 2; ++i)
            a[i] = *(const bh8*)(Abuf + swz128(wm * 32 + 16 * i + (l & 15), krow));
        #pragma unroll
        for (int j = 0; j < 4; ++j)
            b[j] = *(const bh8*)(eW1t + (size_t)(wn * 64 + 16 * j + (l & 15)) * 384 + krow);
        #pragma unroll
        for (int i = 0; i < 2; ++i)
            #pragma unroll
            for (int j = 0; j < 4; ++j)
                acc[i][j] = mfma16(a[i], b[j], acc[i][j]);
    }

    // combine gathered tables -> Sbuf (bf16 sum), then make visible
    #pragma unroll
    for (int it = 0; it < 4; ++it) {
        int c = tid + 512 * it;
        int row = c >> 5, cc = (c & 31) * 8;
        bh8 v;
        #pragma unroll
        for (int q = 0; q < 8; ++q) v[q] = f2b(b2f(ts[it][q]) + b2f(tr[it][q]));
        *(bh8*)(Sbuf + swz256(row, cc)) = v;
    }
    __syncthreads();

    // epilogue 1: + table-sum + eb1, LN partial sums
    float eb1c[4], egc[4], ebtc[4];
    #pragma unroll
    for (int j = 0; j < 4; ++j) {
        int col = wn * 64 + 16 * j + (l & 15);
        eb1c[j] = eb1[col]; egc[j] = eg[col]; ebtc[j] = ebt[col];
    }
    #pragma unroll
    for (int i = 0; i < 2; ++i)
        #pragma unroll
        for (int r = 0; r < 4; ++r) {
            int row = wm * 32 + 16 * i + (l >> 4) * 4 + r;
            float s = 0.f, q = 0.f;
            #pragma unroll
            for (int j = 0; j < 4; ++j) {
                int col = wn * 64 + 16 * j + (l & 15);
                float v = acc[i][j][r] + eb1c[j] +
                          b2f(*(const short*)(Sbuf + swz256(row, col)));
                acc[i][j][r] = v;
                s += v; q += v * v;
            }
            #pragma unroll
            for (int m = 1; m < 16; m <<= 1) {
                s += __shfl_xor(s, m);
                q += __shfl_xor(q, m);
            }
            if ((l & 15) == 0) { P[row][wn][0] = s; P[row][wn][1] = q; }
        }
    __syncthreads();   // all Sbuf reads done; partials visible

    // epilogue 2: LN + relu -> bf16 H (overwrites Sbuf, same-thread positions)
    #pragma unroll
    for (int i = 0; i < 2; ++i)
        #pragma unroll
        for (int r = 0; r < 4; ++r) {
            int row = wm * 32 + 16 * i + (l >> 4) * 4 + r;
            float s = P[row][0][0] + P[row][1][0] + P[row][2][0] + P[row][3][0];
            float q = P[row][0][1] + P[row][1][1] + P[row][2][1] + P[row][3][1];
            float mean = s * (1.0f / 256.0f);
            float var = q * (1.0f / 256.0f) - mean * mean;
            float rstd = rsqrtf(var + LN_EPS);
            #pragma unroll
            for (int j = 0; j < 4; ++j) {
                int col = wn * 64 + 16 * j + (l & 15);
                float v = (acc[i][j][r] - mean) * rstd * egc[j] + ebtc[j];
                v = fmaxf(v, 0.0f);
                *(short*)(Sbuf + swz256(row, col)) = f2b(v);
            }
        }
    __syncthreads();

    // GEMM2: H[64x256] @ eW2 -> [64x128]; wave = 16 rows x 64 cols
    const int wm2 = wid >> 1, wn2 = wid & 1;
    fx4 acc2[4] = {};
    #pragma unroll
    for (int kk = 0; kk < 8; ++kk) {
        int krow = kk * 32 + (l >> 4) * 8;
        bh8 a = *(const bh8*)(Sbuf + swz256(wm2 * 16 + (l & 15), krow));
        #pragma unroll
        for (int j = 0; j < 4; ++j) {
            bh8 b = *(const bh8*)(eW2t + (size_t)(wn2 * 64 + 16 * j + (l & 15)) * 256 + krow);
            acc2[j] = mfma16(a, b, acc2[j]);
        }
    }
    float eb2c[4];
    #pragma unroll
    for (int j = 0; j < 4; ++j) eb2c[j] = eb2[wn2 * 64 + 16 * j + (l & 15)];
    #pragma unroll
    for (int r = 0; r < 4; ++r) {
        int row = wm2 * 16 + (l >> 4) * 4 + r;
        int e = e0 + row;
        if (e < E_CNT) {
            int rcv = irecv[row];
            #pragma unroll
            for (int j = 0; j < 4; ++j) {
                int col = wn2 * 64 + 16 * j + (l & 15);
                float upd = acc2[j][r] + eb2c[j];
                float res = b2f(*(const short*)(Abuf + swz128(row, col)));
                edges_out[(size_t)e * DD + col] = upd + res;
                atomicAdd(agg + (size_t)rcv * DD + col, upd);
            }
        }
    }
}

// ---------------------------------------------------------------------------
// Node kernel: nx=[nodes|agg] (K=256) -> LN/relu -> @nW2 + nb2 + nodes
// ---------------------------------------------------------------------------
__launch_bounds__(512, 2)
__global__ void node_kernel(const float* __restrict__ nodes,
                            const float* __restrict__ agg,
                            const short* __restrict__ nW1t,   // [256][256]
                            const short* __restrict__ nW2t,   // [128][256]
                            const float* __restrict__ nb1,
                            const float* __restrict__ ng,
                            const float* __restrict__ nbt,
                            const float* __restrict__ nb2,
                            float* __restrict__ nodes_out) {
    __shared__ char Abuf[128 * 256 * 2];
    __shared__ char Hbuf[128 * 256 * 2];
    __shared__ float P[128][4][2];

    const int tid = threadIdx.x;
    const int l = tid & 63, wid = tid >> 6;
    const int n0 = blockIdx.x * 128;

    for (int it = 0; it < 8; ++it) {
        int c = tid + 512 * it;
        int row = c >> 5, cc = (c & 31) * 8;
        int n = n0 + row; if (n >= N_CNT) n = N_CNT - 1;
        const float* s = (cc < DD) ? (nodes + (size_t)n * DD + cc)
                                   : (agg + (size_t)n * DD + (cc - DD));
        *(bh8*)(Abuf + swz256(row, cc)) = pack8(s);
    }
    __syncthreads();

    const int wm = wid >> 2, wn = wid & 3;
    fx4 acc[4][4] = {};
    #pragma unroll
    for (int kk = 0; kk < 8; ++kk) {
        int krow = kk * 32 + (l >> 4) * 8;
        bh8 a[4], b[4];
        #pragma unroll
        for (int i = 0; i < 4; ++i)
            a[i] = *(const bh8*)(Abuf + swz256(wm * 64 + 16 * i + (l & 15), krow));
        #pragma unroll
        for (int j = 0; j < 4; ++j)
            b[j] = *(const bh8*)(nW1t + (size_t)(wn * 64 + 16 * j + (l & 15)) * 256 + krow);
        #pragma unroll
        for (int i = 0; i < 4; ++i)
            #pragma unroll
            for (int j = 0; j < 4; ++j)
                acc[i][j] = mfma16(a[i], b[j], acc[i][j]);
    }

    float nb1c[4], ngc[4], nbtc[4];
    #pragma unroll
    for (int j = 0; j < 4; ++j) {
        int col = wn * 64 + 16 * j + (l & 15);
        nb1c[j] = nb1[col]; ngc[j] = ng[col]; nbtc[j] = nbt[col];
    }
    #pragma unroll
    for (int i = 0; i < 4; ++i)
        #pragma unroll
        for (int r = 0; r < 4; ++r) {
            int row = wm * 64 + 16 * i + (l >> 4) * 4 + r;
            float s = 0.f, q = 0.f;
            #pragma unroll
            for (int j = 0; j < 4; ++j) {
                float v = acc[i][j][r] + nb1c[j];
                acc[i][j][r] = v;
                s += v; q += v * v;
            }
            #pragma unroll
            for (int m = 1; m < 16; m <<= 1) {
                s += __shfl_xor(s, m);
                q += __shfl_xor(q, m);
            }
            if ((l & 15) == 0) { P[row][wn][0] = s; P[row][wn][1] = q; }
        }
    __syncthreads();

    #pragma unroll
    for (int i = 0; i < 4; ++i)
        #pragma unroll
        for (int r = 0; r < 4; ++r) {
            int row = wm * 64 + 16 * i + (l >> 4) * 4 + r;
            float s = P[row][0][0] + P[row][1][0] + P[row][2][0] + P[row][3][0];
            float q = P[row][0][1] + P[row][1][1] + P[row][2][1] + P[row][3][1];
            float mean = s * (1.0f / 256.0f);
            float var = q * (1.0f / 256.0f) - mean * mean;
            float rstd = rsqrtf(var + LN_EPS);
            #pragma unroll
            for (int j = 0; j < 4; ++j) {
                int col = wn * 64 + 16 * j + (l & 15);
                float v = (acc[i][j][r] - mean) * rstd * ngc[j] + nbtc[j];
                v = fmaxf(v, 0.0f);
                *(short*)(Hbuf + swz256(row, col)) = f2b(v);
            }
        }
    __syncthreads();

    const int wm2 = wid >> 1, wn2 = wid & 1;
    fx4 acc2[2][4] = {};
    #pragma unroll
    for (int kk = 0; kk < 8; ++kk) {
        int krow = kk * 32 + (l >> 4) * 8;
        bh8 a[2], b[4];
        #pragma unroll
        for (int i = 0; i < 2; ++i)
            a[i] = *(const bh8*)(Hbuf + swz256(wm2 * 32 + 16 * i + (l & 15), krow));
        #pragma unroll
        for (int j = 0; j < 4; ++j)
            b[j] = *(const bh8*)(nW2t + (size_t)(wn2 * 64 + 16 * j + (l & 15)) * 256 + krow);
        #pragma unroll
        for (int i = 0; i < 2; ++i)
            #pragma unroll
            for (int j = 0; j < 4; ++j)
                acc2[i][j] = mfma16(a[i], b[j], acc2[i][j]);
    }
    float nb2c[4];
    #pragma unroll
    for (int j = 0; j < 4; ++j) nb2c[j] = nb2[wn2 * 64 + 16 * j + (l & 15)];
    #pragma unroll
    for (int i = 0; i < 2; ++i)
        #pragma unroll
        for (int r = 0; r < 4; ++r) {
            int row = wm2 * 32 + 16 * i + (l >> 4) * 4 + r;
            int n = n0 + row;
            if (n < N_CNT) {
                #pragma unroll
                for (int j = 0; j < 4; ++j) {
                    int col = wn2 * 64 + 16 * j + (l & 15);
                    float v = acc2[i][j][r] + nb2c[j] + nodes[(size_t)n * DD + col];
                    nodes_out[(size_t)n * DD + col] = v;
                }
            }
        }
}

// ---------------------------------------------------------------------------
extern "C" void kernel_launch(void* const* d_in, const int* in_sizes, int n_in,
                              void* d_out, int out_size, void* d_ws, size_t ws_size,
                              hipStream_t stream) {
    const float* nodes = (const float*)d_in[0];
    const float* edges = (const float*)d_in[1];
    const int* senders = (const int*)d_in[2];
    const int* receivers = (const int*)d_in[3];
    const float* eW1 = (const float*)d_in[4];
    const float* eb1 = (const float*)d_in[5];
    const float* eg  = (const float*)d_in[6];
    const float* ebt = (const float*)d_in[7];
    const float* eW2 = (const float*)d_in[8];
    const float* eb2 = (const float*)d_in[9];
    const float* nW1 = (const float*)d_in[10];
    const float* nb1 = (const float*)d_in[11];
    const float* ng  = (const float*)d_in[12];
    const float* nbt = (const float*)d_in[13];
    const float* nW2 = (const float*)d_in[14];
    const float* nb2 = (const float*)d_in[15];

    char* ws = (char*)d_ws;
    float* agg  = (float*)(ws + 0);             // 25,600,000 B
    short* eW1t = (short*)(ws + 25600000);      //    196,608 B [256][384]
    short* eW2t = (short*)(ws + 25796608);      //     65,536 B [128][256]
    short* nW1t = (short*)(ws + 25862144);      //    131,072 B [256][256]
    short* nW2t = (short*)(ws + 25993216);      //     65,536 B [128][256]
    short* tabS = (short*)(ws + 26058752);      // 25,600,000 B [N][256]
    short* tabR = (short*)(ws + 51658752);      // 25,600,000 B [N][256]

    float* nodes_out = (float*)d_out;
    float* edges_out = nodes_out + (size_t)N_CNT * DD;

    hipMemsetAsync(agg, 0, (size_t)N_CNT * DD * sizeof(float), stream);

    wtrans<<<(384 * 256 + 255) / 256, 256, 0, stream>>>(eW1, eW1t, 384, 256);
    wtrans<<<(256 * 128 + 255) / 256, 256, 0, stream>>>(eW2, eW2t, 256, 128);
    wtrans<<<(256 * 256 + 255) / 256, 256, 0, stream>>>(nW1, nW1t, 256, 256);
    wtrans<<<(256 * 128 + 255) / 256, 256, 0, stream>>>(nW2, nW2t, 256, 128);

    table_kernel<<<(N_CNT + 127) / 128, 512, 0, stream>>>(nodes, eW1t, tabS, tabR);

    edge_kernel<<<(E_CNT + 63) / 64, 512, 0, stream>>>(
        edges, senders, receivers, tabS, tabR, eW1t, eW2t,
        eb1, eg, ebt, eb2, agg, edges_out);

    node_kernel<<<(N_CNT + 127) / 128, 512, 0, stream>>>(
        nodes, agg, nW1t, nW2t, nb1, ng, nbt, nb2, nodes_out);
}